// Round 3
// baseline (594.856 us; speedup 1.0000x reference)
//
#include <hip/hip_runtime.h>
#include <hip/hip_bf16.h>

// LSTM cell, R6 = R5 + bijective XCD-chunked block swizzle (single-variable A/B).
// Theory: R5's 8-phase ran at 1 block/CU with no XCD swizzle -> every XCD
// touched all 16 B panels/round (32MB >> 4MB L2) -> staging served from
// LLC/fabric at ~500+cyc -> counted-vmcnt stalls ate the pipeline.
// Remap: XCD x owns 64 contiguous logical tiles = 4 B-panel rows (2/round =
// 4MB, L2-resident). 512 % 8 == 0 -> (bid&7)*64 + (bid>>3) is bijective.
// All else identical to R5 (verified-correct schedule, 0 bank conflicts).

#define BATCH 4096
#define HID   2048
#define KDIM  2048
#define K4    4096
#define LDK   72      // fallback kernel's padded LDS stride

typedef __attribute__((ext_vector_type(8))) short  short8;
typedef __attribute__((ext_vector_type(4))) float  f32x4;

__device__ __forceinline__ float sigm(float x)  { return 1.f / (1.f + __expf(-x)); }
__device__ __forceinline__ float tanhx(float x) { return 2.f / (1.f + __expf(-2.f * x)) - 1.f; }

__device__ __forceinline__ uint2 pk_bf16x4(float4 v) {
  __hip_bfloat162 lo = __float22bfloat162_rn(make_float2(v.x, v.y));
  __hip_bfloat162 hi = __float22bfloat162_rn(make_float2(v.z, v.w));
  uint2 r;
  r.x = *(unsigned*)&lo;
  r.y = *(unsigned*)&hi;
  return r;
}

__device__ __forceinline__ void gload16(const void* g, void* l) {
  __builtin_amdgcn_global_load_lds(
      (const __attribute__((address_space(1))) unsigned int*)g,
      (__attribute__((address_space(3))) unsigned int*)l, 16, 0, 0);
}

#define BAR()  asm volatile("s_barrier" ::: "memory")
#define LGK0() asm volatile("s_waitcnt lgkmcnt(0)" ::: "memory")
#define VMC(n) asm volatile("s_waitcnt vmcnt(" #n ")" ::: "memory")

// ---------------- conversion pass 1: Acat = bf16([X | Hx]) ------------------
__global__ __launch_bounds__(256) void conv_a(const float* __restrict__ X,
                                              const float* __restrict__ Hx,
                                              short* __restrict__ A) {
  const int gid = blockIdx.x * 256 + threadIdx.x;
  const int m   = gid >> 9;
  const int pos = (gid & 511) << 3;
  const float* src = (pos < KDIM) ? X  + (size_t)m * KDIM + pos
                                  : Hx + (size_t)m * KDIM + (pos - KDIM);
  float4 v0 = *(const float4*)src;
  float4 v1 = *(const float4*)(src + 4);
  uint2 p0 = pk_bf16x4(v0), p1 = pk_bf16x4(v1);
  uint4 o; o.x = p0.x; o.y = p0.y; o.z = p1.x; o.w = p1.y;
  *(uint4*)(A + (size_t)gid * 8) = o;
}

// ------ conversion pass 2: Bcat[j'=4h+g][k] = bf16([Wx | Wh][g*2048+h]) -----
__global__ __launch_bounds__(256) void conv_b(const float* __restrict__ Wx,
                                              const float* __restrict__ Wh,
                                              short* __restrict__ Bm) {
  const int gid = blockIdx.x * 256 + threadIdx.x;
  const int jp  = gid >> 9;
  const int pos = (gid & 511) << 3;
  const int srow = (jp & 3) * HID + (jp >> 2);
  const float* src = (pos < KDIM) ? Wx + (size_t)srow * KDIM + pos
                                  : Wh + (size_t)srow * KDIM + (pos - KDIM);
  float4 v0 = *(const float4*)src;
  float4 v1 = *(const float4*)(src + 4);
  uint2 p0 = pk_bf16x4(v0), p1 = pk_bf16x4(v1);
  uint4 o; o.x = p0.x; o.y = p0.y; o.z = p1.x; o.w = p1.y;
  *(uint4*)(Bm + (size_t)gid * 8) = o;
}

// ---------------- helpers for the 8-phase kernel ----------------------------
__device__ __forceinline__ void lda4(short8 (&dst)[8], const short* base,
                                     int arow, int sx0, int sx1, int mfb) {
  #pragma unroll
  for (int u = 0; u < 4; ++u) {
    dst[u]     = *(const short8*)&base[arow + (mfb + u) * 1024 + sx0];
    dst[4 + u] = *(const short8*)&base[arow + (mfb + u) * 1024 + sx1];
  }
}
__device__ __forceinline__ void ldb2(short8 (&dst)[4], const short* base,
                                     int brow, int sx0, int sx1, int nfb) {
  #pragma unroll
  for (int v = 0; v < 2; ++v) {
    dst[v]     = *(const short8*)&base[brow + (nfb + v) * 1024 + sx0];
    dst[2 + v] = *(const short8*)&base[brow + (nfb + v) * 1024 + sx1];
  }
}
__device__ __forceinline__ void mmq(f32x4 (&acc)[8][4], const short8 (&A)[8],
                                    const short8 (&B)[4], int MB, int NB) {
  __builtin_amdgcn_s_setprio(1);
  #pragma unroll
  for (int ks = 0; ks < 2; ++ks)
    #pragma unroll
    for (int u = 0; u < 4; ++u)
      #pragma unroll
      for (int v = 0; v < 2; ++v)
        acc[MB + u][NB + v] = __builtin_amdgcn_mfma_f32_16x16x32_bf16(
            A[ks * 4 + u], B[ks * 2 + v], acc[MB + u][NB + v], 0, 0, 0);
  __builtin_amdgcn_s_setprio(0);
}

// ---------------- main GEMM + LSTM epilogue (256^2, 8-phase) ----------------
__global__ __launch_bounds__(512, 2) void lstm_mm8(
    const short* __restrict__ A, const short* __restrict__ Bm,
    const float* __restrict__ Cx,
    const float* __restrict__ bx, const float* __restrict__ bh,
    float* __restrict__ Hy, float* __restrict__ Cy)
{
  __shared__ __align__(16) short A_sh[2 * 16384];  // [d][256 rows][64], 64 KiB
  __shared__ __align__(16) short B_sh[2 * 16384];  // [d][256 rows][64], 64 KiB

  const int tid  = threadIdx.x;
  const int wv   = tid >> 6;         // 0..7
  const int lane = tid & 63;
  const int quad = lane >> 4;
  const int ln   = lane & 15;
  const int wm   = wv >> 2;          // 2 waves in M
  const int wn   = wv & 3;           // 4 waves in N

  // XCD-chunked bijective swizzle: dispatch order bid = y*16+x round-robins
  // XCDs on bid&7. Give XCD q the 64 logical tiles with ty in [4q, 4q+4):
  // per round each XCD touches 2 B panels (4MB -> L2-resident) and its A
  // panels are read concurrently by its 2 active y-rows.
  const int bid = blockIdx.y * 16 + blockIdx.x;
  const int kk  = bid >> 3;
  const int ty  = (bid & 7) * 4 + (kk >> 4);   // 0..31
  const int tx  = kk & 15;                     // 0..15
  const int m0  = tx * 256;
  const int j0  = ty * 256;
  const int h0  = ty * 64;

  f32x4 acc[8][4];
  #pragma unroll
  for (int a = 0; a < 8; ++a)
    #pragma unroll
    for (int b = 0; b < 4; ++b)
      acc[a][b] = (f32x4){0.f, 0.f, 0.f, 0.f};

  // staging: per wave, one half-tile (128x64) = 2 gload16 issues (16 rows of
  // wave's slice). LDS dest linear, global source pre-swizzled: slot^row&7.
  const int l8  = lane >> 3;
  const int swz = ((lane & 7) ^ (l8 & 7)) << 3;
  const short* aG = A  + (size_t)(m0 + l8) * K4 + swz;
  const short* bG = Bm + (size_t)(j0 + l8) * K4 + swz;

  #define STAGE_A(d, h, tau) do {                                             \
    gload16(aG + ((size_t)((h)*128 + wv*16    )) * K4 + (tau)*64,             \
            &A_sh[(d)*16384 + (h)*8192 + wv*1024]);                           \
    gload16(aG + ((size_t)((h)*128 + wv*16 + 8)) * K4 + (tau)*64,             \
            &A_sh[(d)*16384 + (h)*8192 + wv*1024 + 512]);                     \
  } while (0)
  #define STAGE_B(d, h, tau) do {                                             \
    gload16(bG + ((size_t)((h)*128 + wv*16    )) * K4 + (tau)*64,             \
            &B_sh[(d)*16384 + (h)*8192 + wv*1024]);                           \
    gload16(bG + ((size_t)((h)*128 + wv*16 + 8)) * K4 + (tau)*64,             \
            &B_sh[(d)*16384 + (h)*8192 + wv*1024 + 512]);                     \
  } while (0)

  // ds_read geometry (XOR slot swizzle; measured 0 bank conflicts)
  const int arow = (wm * 128 + ln) * 64;   // shorts
  const int brow = (wn * 64  + ln) * 64;
  const int sx0  = ((0 + quad) ^ (ln & 7)) << 3;
  const int sx1  = ((4 + quad) ^ (ln & 7)) << 3;

  // prologue: tile0 -> dbuf0 (4 halves), tile1 -> dbuf1 (3 halves; B-h1 of
  // tile1 is staged at ph1 of iteration 0). 14 loads; vmcnt(6) => tile0 done.
  STAGE_A(0, 0, 0); STAGE_A(0, 1, 0); STAGE_B(0, 0, 0); STAGE_B(0, 1, 0);
  STAGE_A(1, 0, 1); STAGE_A(1, 1, 1); STAGE_B(1, 0, 1);
  VMC(6);
  BAR();

  short8 aQ0[8], aQ1[8], bLo[4], bHi[4];

  #pragma unroll 1
  for (int i = 0; i < 32; ++i) {
    const int  S0 = 2 * i + 2, S1 = 2 * i + 3, T1k = 2 * i + 1;
    const bool nl = (i != 31);
    // ---- ph1: read A(mf0-3)+B(nf0-1) of dbuf0; stage dbuf1.B-h1 <- T1 ----
    lda4(aQ0, &A_sh[0], arow, sx0, sx1, 0);
    ldb2(bLo, &B_sh[0], brow, sx0, sx1, 0);
    STAGE_B(1, 1, T1k);
    BAR(); LGK0();
    mmq(acc, aQ0, bLo, 0, 0);
    BAR();
    // ---- ph2: read A(mf4-7) dbuf0 ----------------------------------------
    lda4(aQ1, &A_sh[0], arow, sx0, sx1, 4);
    BAR(); LGK0();
    mmq(acc, aQ1, bLo, 4, 0);
    BAR();
    // ---- ph3: read B(nf2-3) dbuf0; stage dbuf0.A-h0 <- S0 ----------------
    ldb2(bHi, &B_sh[0], brow, sx0, sx1, 2);
    if (nl) STAGE_A(0, 0, S0);
    BAR(); LGK0();
    mmq(acc, aQ1, bHi, 4, 2);
    BAR();
    // ---- ph4: stage dbuf0.B-h0 <- S0; vmcnt(4) => dbuf1 tile T1 landed ---
    if (nl) STAGE_B(0, 0, S0);
    BAR();
    mmq(acc, aQ0, bHi, 0, 2);
    if (nl) { VMC(4); } else { VMC(0); }
    BAR();
    // ---- ph5: read A(mf0-3)+B(nf0-1) of dbuf1; stage dbuf0.A-h1 ----------
    lda4(aQ0, &A_sh[16384], arow, sx0, sx1, 0);
    ldb2(bLo, &B_sh[16384], brow, sx0, sx1, 0);
    if (nl) STAGE_A(0, 1, S0);
    BAR(); LGK0();
    mmq(acc, aQ0, bLo, 0, 0);
    BAR();
    // ---- ph6: read A(mf4-7) dbuf1; stage dbuf0.B-h1 ----------------------
    lda4(aQ1, &A_sh[16384], arow, sx0, sx1, 4);
    if (nl) STAGE_B(0, 1, S0);
    BAR(); LGK0();
    mmq(acc, aQ1, bLo, 4, 0);
    BAR();
    // ---- ph7: read B(nf2-3) dbuf1; stage dbuf1.A-h0 <- S1 ----------------
    ldb2(bHi, &B_sh[16384], brow, sx0, sx1, 2);
    if (nl) STAGE_A(1, 0, S1);
    BAR(); LGK0();
    mmq(acc, aQ1, bHi, 4, 2);
    BAR();
    // ---- ph8: stage dbuf1.B-h0 + dbuf1.A-h1 <- S1; vmcnt(6) --------------
    if (nl) { STAGE_B(1, 0, S1); STAGE_A(1, 1, S1); }
    BAR();
    mmq(acc, aQ0, bHi, 0, 2);
    if (nl) { VMC(6); }
    BAR();
  }
  #undef STAGE_A
  #undef STAGE_B

  // ---- epilogue: C/D layout col = lane&15 (c), row = quad*4 + reg ----
  const int g = lane & 3;            // gate of this lane (c&3)
  float biasv[4];
  int   hgs[4];
  #pragma unroll
  for (int nf = 0; nf < 4; ++nf) {
    int c  = wn * 64 + nf * 16 + ln;
    int hg = h0 + (c >> 2);
    hgs[nf] = hg;
    int j = g * HID + hg;
    biasv[nf] = bx[j] + bh[j];
  }
  #pragma unroll
  for (int mf = 0; mf < 8; ++mf) {
    #pragma unroll
    for (int r = 0; r < 4; ++r) {
      int mrow = m0 + wm * 128 + mf * 16 + quad * 4 + r;
      #pragma unroll
      for (int nf = 0; nf < 4; ++nf) {
        float v   = acc[mf][nf][r] + biasv[nf];
        float act = (g == 2) ? tanhx(v) : sigm(v);
        float y1 = __shfl_xor(act, 1);
        float y2 = __shfl_xor(act, 2);
        float y3 = __shfl_xor(act, 3);
        float ft = (g == 0) ? act : ((g == 1) ? y1 : ((g == 2) ? y2 : y3));
        float it = (g == 1) ? act : ((g == 0) ? y1 : ((g == 3) ? y2 : y3));
        float gt = (g == 2) ? act : ((g == 3) ? y1 : ((g == 0) ? y2 : y3));
        float ot = (g == 3) ? act : ((g == 2) ? y1 : ((g == 1) ? y2 : y3));
        if (g < 2) {
          size_t off = (size_t)mrow * HID + hgs[nf];
          float cxv = Cx[off];
          float cyv = ft * cxv + it * gt;
          if (g == 0) Hy[off] = ot * tanhx(cyv);
          else        Cy[off] = cyv;
        }
      }
    }
  }
}

// ---------------- fallback: R3 kernel (register staging, fp32 in) ----------
__global__ __launch_bounds__(256) void lstm_cell_fallback(
    const float* __restrict__ X, const float* __restrict__ Hx,
    const float* __restrict__ Cx,
    const float* __restrict__ Wx, const float* __restrict__ bx,
    const float* __restrict__ Wh, const float* __restrict__ bh,
    float* __restrict__ Hy, float* __restrict__ Cy)
{
  __shared__ __align__(16) short A_lds[128 * LDK];
  __shared__ __align__(16) short B_lds[128 * LDK];

  const int tid  = threadIdx.x;
  const int wv   = tid >> 6;
  const int lane = tid & 63;
  const int quad = lane >> 4;
  const int ln   = lane & 15;
  const int wm   = wv >> 1;
  const int wn   = wv & 1;
  const int m0   = blockIdx.x * 128;
  const int h0   = blockIdx.y * 32;

  f32x4 acc[4][4];
  #pragma unroll
  for (int a = 0; a < 4; ++a)
    #pragma unroll
    for (int b = 0; b < 4; ++b)
      acc[a][b] = (f32x4){0.f, 0.f, 0.f, 0.f};

  const int rA  = tid >> 4;
  const int kc4 = (tid & 15) * 4;
  size_t aoff[8], boff[8];
  int    lrow[8];
  #pragma unroll
  for (int q = 0; q < 8; ++q) {
    int row  = q * 16 + rA;
    lrow[q]  = row;
    aoff[q]  = (size_t)(m0 + row) * KDIM + kc4;
    int wrow = (row & 3) * HID + h0 + (row >> 2);
    boff[q]  = (size_t)wrow * KDIM + kc4;
  }

  const int NT = 2 * (KDIM / 64);
  float4 areg[8], breg[8];
  #pragma unroll
  for (int q = 0; q < 8; ++q) {
    areg[q] = *(const float4*)(X  + aoff[q]);
    breg[q] = *(const float4*)(Wx + boff[q]);
  }

  for (int t = 0; t < NT; ++t) {
    __syncthreads();
    #pragma unroll
    for (int q = 0; q < 8; ++q) {
      *(uint2*)&A_lds[lrow[q] * LDK + kc4] = pk_bf16x4(areg[q]);
      *(uint2*)&B_lds[lrow[q] * LDK + kc4] = pk_bf16x4(breg[q]);
    }
    __syncthreads();
    if (t + 1 < NT) {
      const float* Ap = (t + 1 < 32) ? X  : Hx;
      const float* Wp = (t + 1 < 32) ? Wx : Wh;
      const int k0 = ((t + 1) & 31) * 64;
      #pragma unroll
      for (int q = 0; q < 8; ++q) {
        areg[q] = *(const float4*)(Ap + aoff[q] + k0);
        breg[q] = *(const float4*)(Wp + boff[q] + k0);
      }
    }
    #pragma unroll
    for (int ks = 0; ks < 2; ++ks) {
      short8 af[4], bfv[4];
      #pragma unroll
      for (int u = 0; u < 4; ++u)
        af[u] = *(const short8*)&A_lds[(wm * 64 + u * 16 + ln) * LDK + ks * 32 + quad * 8];
      #pragma unroll
      for (int u = 0; u < 4; ++u)
        bfv[u] = *(const short8*)&B_lds[(wn * 64 + u * 16 + ln) * LDK + ks * 32 + quad * 8];
      #pragma unroll
      for (int tm = 0; tm < 4; ++tm)
        #pragma unroll
        for (int tn = 0; tn < 4; ++tn)
          acc[tm][tn] = __builtin_amdgcn_mfma_f32_16x16x32_bf16(
              af[tm], bfv[tn], acc[tm][tn], 0, 0, 0);
    }
  }

  const int g = lane & 3;
  float biasv[4];
  int   hgs[4];
  #pragma unroll
  for (int tn = 0; tn < 4; ++tn) {
    int c  = wn * 64 + tn * 16 + ln;
    int hg = h0 + (c >> 2);
    hgs[tn] = hg;
    int j = g * HID + hg;
    biasv[tn] = bx[j] + bh[j];
  }
  #pragma unroll
  for (int tm = 0; tm < 4; ++tm) {
    #pragma unroll
    for (int r = 0; r < 4; ++r) {
      int mrow = m0 + wm * 64 + tm * 16 + quad * 4 + r;
      #pragma unroll
      for (int tn = 0; tn < 4; ++tn) {
        float v   = acc[tm][tn][r] + biasv[tn];
        float act = (g == 2) ? tanhx(v) : sigm(v);
        float y1 = __shfl_xor(act, 1);
        float y2 = __shfl_xor(act, 2);
        float y3 = __shfl_xor(act, 3);
        float ft = (g == 0) ? act : ((g == 1) ? y1 : ((g == 2) ? y2 : y3));
        float it = (g == 1) ? act : ((g == 0) ? y1 : ((g == 3) ? y2 : y3));
        float gt = (g == 2) ? act : ((g == 3) ? y1 : ((g == 0) ? y2 : y3));
        float ot = (g == 3) ? act : ((g == 2) ? y1 : ((g == 1) ? y2 : y3));
        if (g < 2) {
          size_t off = (size_t)mrow * HID + hgs[tn];
          float cxv = Cx[off];
          float cyv = ft * cxv + it * gt;
          if (g == 0) Hy[off] = ot * tanhx(cyv);
          else        Cy[off] = cyv;
        }
      }
    }
  }
}

extern "C" void kernel_launch(void* const* d_in, const int* in_sizes, int n_in,
                              void* d_out, int out_size, void* d_ws, size_t ws_size,
                              hipStream_t stream) {
  const float* X  = (const float*)d_in[0];
  const float* Hx = (const float*)d_in[1];
  const float* Cx = (const float*)d_in[2];
  const float* Wx = (const float*)d_in[3];
  const float* bx = (const float*)d_in[4];
  const float* Wh = (const float*)d_in[5];
  const float* bh = (const float*)d_in[6];
  float*       Hy = (float*)d_out;
  float*       Cy = Hy + (size_t)BATCH * HID;

  const size_t needA = (size_t)BATCH * K4 * sizeof(short);     // 32 MiB
  const size_t needB = (size_t)(4 * HID) * K4 * sizeof(short); // 64 MiB

  if (d_ws != nullptr && ws_size >= needA + needB) {
    short* Abf = (short*)d_ws;
    short* Bbf = (short*)((char*)d_ws + needA);
    conv_a<<<dim3((BATCH * (K4 / 8)) / 256), dim3(256), 0, stream>>>(X, Hx, Abf);
    conv_b<<<dim3((4 * HID * (K4 / 8)) / 256), dim3(256), 0, stream>>>(Wx, Wh, Bbf);
    dim3 grid(BATCH / 256, (4 * HID) / 256, 1);  // remapped inside the kernel
    lstm_mm8<<<grid, dim3(512, 1, 1), 0, stream>>>(Abf, Bbf, Cx, bx, bh, Hy, Cy);
  } else {
    dim3 grid(BATCH / 128, HID / 32, 1);
    lstm_cell_fallback<<<grid, dim3(256, 1, 1), 0, stream>>>(X, Hx, Cx, Wx, bx, Wh, bh, Hy, Cy);
  }
}

// Round 4
// 585.119 us; speedup vs baseline: 1.0166x; 1.0166x over previous
//
#include <hip/hip_runtime.h>
#include <hip/hip_bf16.h>

// LSTM cell, R7 = R5 schedule rebuilt for uniform 4-phase prefetch distance.
// R6 post-mortem: XCD swizzle regressed (383->466), FETCH unchanged -> revert.
// R5 flaw: tightest staged-half->vmcnt-gate distance was 2 phases (B-h1@ph6
// gated ph8) -> guaranteed stall at ~600-900cy load latency with 1 block/CU.
// R7: ph4/ph8 burst-stage a WHOLE next tile (8 gload16) into the buffer just
// finished reading; each gate vmcnt(8) then waits only on the tile staged 4
// MFMA phases earlier. ph4/ph8 quadrant (0,2) uses registers only (aQ0/bHi),
// so those phases have no ds_reads. Everything else identical to R5.

#define BATCH 4096
#define HID   2048
#define KDIM  2048
#define K4    4096
#define LDK   72      // fallback kernel's padded LDS stride

typedef __attribute__((ext_vector_type(8))) short  short8;
typedef __attribute__((ext_vector_type(4))) float  f32x4;

__device__ __forceinline__ float sigm(float x)  { return 1.f / (1.f + __expf(-x)); }
__device__ __forceinline__ float tanhx(float x) { return 2.f / (1.f + __expf(-2.f * x)) - 1.f; }

__device__ __forceinline__ uint2 pk_bf16x4(float4 v) {
  __hip_bfloat162 lo = __float22bfloat162_rn(make_float2(v.x, v.y));
  __hip_bfloat162 hi = __float22bfloat162_rn(make_float2(v.z, v.w));
  uint2 r;
  r.x = *(unsigned*)&lo;
  r.y = *(unsigned*)&hi;
  return r;
}

__device__ __forceinline__ void gload16(const void* g, void* l) {
  __builtin_amdgcn_global_load_lds(
      (const __attribute__((address_space(1))) unsigned int*)g,
      (__attribute__((address_space(3))) unsigned int*)l, 16, 0, 0);
}

#define BAR()  asm volatile("s_barrier" ::: "memory")
#define LGK0() asm volatile("s_waitcnt lgkmcnt(0)" ::: "memory")
#define VMC(n) asm volatile("s_waitcnt vmcnt(" #n ")" ::: "memory")

// ---------------- conversion pass 1: Acat = bf16([X | Hx]) ------------------
__global__ __launch_bounds__(256) void conv_a(const float* __restrict__ X,
                                              const float* __restrict__ Hx,
                                              short* __restrict__ A) {
  const int gid = blockIdx.x * 256 + threadIdx.x;
  const int m   = gid >> 9;
  const int pos = (gid & 511) << 3;
  const float* src = (pos < KDIM) ? X  + (size_t)m * KDIM + pos
                                  : Hx + (size_t)m * KDIM + (pos - KDIM);
  float4 v0 = *(const float4*)src;
  float4 v1 = *(const float4*)(src + 4);
  uint2 p0 = pk_bf16x4(v0), p1 = pk_bf16x4(v1);
  uint4 o; o.x = p0.x; o.y = p0.y; o.z = p1.x; o.w = p1.y;
  *(uint4*)(A + (size_t)gid * 8) = o;
}

// ------ conversion pass 2: Bcat[j'=4h+g][k] = bf16([Wx | Wh][g*2048+h]) -----
__global__ __launch_bounds__(256) void conv_b(const float* __restrict__ Wx,
                                              const float* __restrict__ Wh,
                                              short* __restrict__ Bm) {
  const int gid = blockIdx.x * 256 + threadIdx.x;
  const int jp  = gid >> 9;
  const int pos = (gid & 511) << 3;
  const int srow = (jp & 3) * HID + (jp >> 2);
  const float* src = (pos < KDIM) ? Wx + (size_t)srow * KDIM + pos
                                  : Wh + (size_t)srow * KDIM + (pos - KDIM);
  float4 v0 = *(const float4*)src;
  float4 v1 = *(const float4*)(src + 4);
  uint2 p0 = pk_bf16x4(v0), p1 = pk_bf16x4(v1);
  uint4 o; o.x = p0.x; o.y = p0.y; o.z = p1.x; o.w = p1.y;
  *(uint4*)(Bm + (size_t)gid * 8) = o;
}

// ---------------- helpers for the 8-phase kernel ----------------------------
__device__ __forceinline__ void lda4(short8 (&dst)[8], const short* base,
                                     int arow, int sx0, int sx1, int mfb) {
  #pragma unroll
  for (int u = 0; u < 4; ++u) {
    dst[u]     = *(const short8*)&base[arow + (mfb + u) * 1024 + sx0];
    dst[4 + u] = *(const short8*)&base[arow + (mfb + u) * 1024 + sx1];
  }
}
__device__ __forceinline__ void ldb2(short8 (&dst)[4], const short* base,
                                     int brow, int sx0, int sx1, int nfb) {
  #pragma unroll
  for (int v = 0; v < 2; ++v) {
    dst[v]     = *(const short8*)&base[brow + (nfb + v) * 1024 + sx0];
    dst[2 + v] = *(const short8*)&base[brow + (nfb + v) * 1024 + sx1];
  }
}
__device__ __forceinline__ void mmq(f32x4 (&acc)[8][4], const short8 (&A)[8],
                                    const short8 (&B)[4], int MB, int NB) {
  __builtin_amdgcn_s_setprio(1);
  #pragma unroll
  for (int ks = 0; ks < 2; ++ks)
    #pragma unroll
    for (int u = 0; u < 4; ++u)
      #pragma unroll
      for (int v = 0; v < 2; ++v)
        acc[MB + u][NB + v] = __builtin_amdgcn_mfma_f32_16x16x32_bf16(
            A[ks * 4 + u], B[ks * 2 + v], acc[MB + u][NB + v], 0, 0, 0);
  __builtin_amdgcn_s_setprio(0);
}

// ---------------- main GEMM + LSTM epilogue (256^2, 8-phase) ----------------
__global__ __launch_bounds__(512, 2) void lstm_mm8(
    const short* __restrict__ A, const short* __restrict__ Bm,
    const float* __restrict__ Cx,
    const float* __restrict__ bx, const float* __restrict__ bh,
    float* __restrict__ Hy, float* __restrict__ Cy)
{
  __shared__ __align__(16) short A_sh[2 * 16384];  // [d][256 rows][64], 64 KiB
  __shared__ __align__(16) short B_sh[2 * 16384];  // [d][256 rows][64], 64 KiB

  const int tid  = threadIdx.x;
  const int wv   = tid >> 6;         // 0..7
  const int lane = tid & 63;
  const int quad = lane >> 4;
  const int ln   = lane & 15;
  const int wm   = wv >> 2;          // 2 waves in M
  const int wn   = wv & 3;           // 4 waves in N
  const int m0   = blockIdx.x * 256;
  const int j0   = blockIdx.y * 256; // = 4 * h0
  const int h0   = blockIdx.y * 64;

  f32x4 acc[8][4];
  #pragma unroll
  for (int a = 0; a < 8; ++a)
    #pragma unroll
    for (int b = 0; b < 4; ++b)
      acc[a][b] = (f32x4){0.f, 0.f, 0.f, 0.f};

  // staging: per wave, one half-tile (128x64) = 2 gload16 issues (16 rows of
  // wave's slice). LDS dest linear, global source pre-swizzled: slot^row&7.
  const int l8  = lane >> 3;
  const int swz = ((lane & 7) ^ (l8 & 7)) << 3;
  const short* aG = A  + (size_t)(m0 + l8) * K4 + swz;
  const short* bG = Bm + (size_t)(j0 + l8) * K4 + swz;

  #define STAGE_A(d, h, tau) do {                                             \
    gload16(aG + ((size_t)((h)*128 + wv*16    )) * K4 + (tau)*64,             \
            &A_sh[(d)*16384 + (h)*8192 + wv*1024]);                           \
    gload16(aG + ((size_t)((h)*128 + wv*16 + 8)) * K4 + (tau)*64,             \
            &A_sh[(d)*16384 + (h)*8192 + wv*1024 + 512]);                     \
  } while (0)
  #define STAGE_B(d, h, tau) do {                                             \
    gload16(bG + ((size_t)((h)*128 + wv*16    )) * K4 + (tau)*64,             \
            &B_sh[(d)*16384 + (h)*8192 + wv*1024]);                           \
    gload16(bG + ((size_t)((h)*128 + wv*16 + 8)) * K4 + (tau)*64,             \
            &B_sh[(d)*16384 + (h)*8192 + wv*1024 + 512]);                     \
  } while (0)
  // whole next K-tile into dbuf d (4 halves = 8 gload16)
  #define STAGE_TILE(d, tau) do {                                             \
    STAGE_A(d, 0, tau); STAGE_A(d, 1, tau);                                   \
    STAGE_B(d, 0, tau); STAGE_B(d, 1, tau);                                   \
  } while (0)

  // ds_read geometry (XOR slot swizzle; measured 0 bank conflicts)
  const int arow = (wm * 128 + ln) * 64;   // shorts
  const int brow = (wn * 64  + ln) * 64;
  const int sx0  = ((0 + quad) ^ (ln & 7)) << 3;
  const int sx1  = ((4 + quad) ^ (ln & 7)) << 3;

  // prologue: tile0 -> dbuf0, tile1 -> dbuf1; vmcnt(8) => tile0 landed.
  STAGE_TILE(0, 0);
  STAGE_TILE(1, 1);
  VMC(8);
  BAR();

  short8 aQ0[8], aQ1[8], bLo[4], bHi[4];

  #pragma unroll 1
  for (int i = 0; i < 32; ++i) {
    const int  S0 = 2 * i + 2, S1 = 2 * i + 3;
    const bool nl = (i != 31);
    // ---- ph1: read A(mf0-3)+B(nf0-1) of dbuf0 ----------------------------
    lda4(aQ0, &A_sh[0], arow, sx0, sx1, 0);
    ldb2(bLo, &B_sh[0], brow, sx0, sx1, 0);
    BAR(); LGK0();
    mmq(acc, aQ0, bLo, 0, 0);
    BAR();
    // ---- ph2: read A(mf4-7) dbuf0 ----------------------------------------
    lda4(aQ1, &A_sh[0], arow, sx0, sx1, 4);
    BAR(); LGK0();
    mmq(acc, aQ1, bLo, 4, 0);
    BAR();
    // ---- ph3: read B(nf2-3) dbuf0 ----------------------------------------
    ldb2(bHi, &B_sh[0], brow, sx0, sx1, 2);
    BAR(); LGK0();
    mmq(acc, aQ1, bHi, 4, 2);
    BAR();
    // ---- ph4: burst-stage dbuf0 <- tile S0; reg-only quadrant; gate dbuf1
    if (nl) STAGE_TILE(0, S0);
    mmq(acc, aQ0, bHi, 0, 2);
    if (nl) { VMC(8); } else { VMC(0); }
    BAR();
    // ---- ph5: read A(mf0-3)+B(nf0-1) of dbuf1 ----------------------------
    lda4(aQ0, &A_sh[16384], arow, sx0, sx1, 0);
    ldb2(bLo, &B_sh[16384], brow, sx0, sx1, 0);
    BAR(); LGK0();
    mmq(acc, aQ0, bLo, 0, 0);
    BAR();
    // ---- ph6: read A(mf4-7) dbuf1 ----------------------------------------
    lda4(aQ1, &A_sh[16384], arow, sx0, sx1, 4);
    BAR(); LGK0();
    mmq(acc, aQ1, bLo, 4, 0);
    BAR();
    // ---- ph7: read B(nf2-3) dbuf1 ----------------------------------------
    ldb2(bHi, &B_sh[16384], brow, sx0, sx1, 2);
    BAR(); LGK0();
    mmq(acc, aQ1, bHi, 4, 2);
    BAR();
    // ---- ph8: burst-stage dbuf1 <- tile S1; reg-only quadrant; gate dbuf0
    if (nl) STAGE_TILE(1, S1);
    mmq(acc, aQ0, bHi, 0, 2);
    if (nl) { VMC(8); }
    BAR();
  }
  #undef STAGE_TILE
  #undef STAGE_A
  #undef STAGE_B

  // ---- epilogue: C/D layout col = lane&15 (c), row = quad*4 + reg ----
  const int g = lane & 3;            // gate of this lane (c&3)
  float biasv[4];
  int   hgs[4];
  #pragma unroll
  for (int nf = 0; nf < 4; ++nf) {
    int c  = wn * 64 + nf * 16 + ln;
    int hg = h0 + (c >> 2);
    hgs[nf] = hg;
    int j = g * HID + hg;
    biasv[nf] = bx[j] + bh[j];
  }
  #pragma unroll
  for (int mf = 0; mf < 8; ++mf) {
    #pragma unroll
    for (int r = 0; r < 4; ++r) {
      int mrow = m0 + wm * 128 + mf * 16 + quad * 4 + r;
      #pragma unroll
      for (int nf = 0; nf < 4; ++nf) {
        float v   = acc[mf][nf][r] + biasv[nf];
        float act = (g == 2) ? tanhx(v) : sigm(v);
        float y1 = __shfl_xor(act, 1);
        float y2 = __shfl_xor(act, 2);
        float y3 = __shfl_xor(act, 3);
        float ft = (g == 0) ? act : ((g == 1) ? y1 : ((g == 2) ? y2 : y3));
        float it = (g == 1) ? act : ((g == 0) ? y1 : ((g == 3) ? y2 : y3));
        float gt = (g == 2) ? act : ((g == 3) ? y1 : ((g == 0) ? y2 : y3));
        float ot = (g == 3) ? act : ((g == 2) ? y1 : ((g == 1) ? y2 : y3));
        if (g < 2) {
          size_t off = (size_t)mrow * HID + hgs[nf];
          float cxv = Cx[off];
          float cyv = ft * cxv + it * gt;
          if (g == 0) Hy[off] = ot * tanhx(cyv);
          else        Cy[off] = cyv;
        }
      }
    }
  }
}

// ---------------- fallback: R3 kernel (register staging, fp32 in) ----------
__global__ __launch_bounds__(256) void lstm_cell_fallback(
    const float* __restrict__ X, const float* __restrict__ Hx,
    const float* __restrict__ Cx,
    const float* __restrict__ Wx, const float* __restrict__ bx,
    const float* __restrict__ Wh, const float* __restrict__ bh,
    float* __restrict__ Hy, float* __restrict__ Cy)
{
  __shared__ __align__(16) short A_lds[128 * LDK];
  __shared__ __align__(16) short B_lds[128 * LDK];

  const int tid  = threadIdx.x;
  const int wv   = tid >> 6;
  const int lane = tid & 63;
  const int quad = lane >> 4;
  const int ln   = lane & 15;
  const int wm   = wv >> 1;
  const int wn   = wv & 1;
  const int m0   = blockIdx.x * 128;
  const int h0   = blockIdx.y * 32;

  f32x4 acc[4][4];
  #pragma unroll
  for (int a = 0; a < 4; ++a)
    #pragma unroll
    for (int b = 0; b < 4; ++b)
      acc[a][b] = (f32x4){0.f, 0.f, 0.f, 0.f};

  const int rA  = tid >> 4;
  const int kc4 = (tid & 15) * 4;
  size_t aoff[8], boff[8];
  int    lrow[8];
  #pragma unroll
  for (int q = 0; q < 8; ++q) {
    int row  = q * 16 + rA;
    lrow[q]  = row;
    aoff[q]  = (size_t)(m0 + row) * KDIM + kc4;
    int wrow = (row & 3) * HID + h0 + (row >> 2);
    boff[q]  = (size_t)wrow * KDIM + kc4;
  }

  const int NT = 2 * (KDIM / 64);
  float4 areg[8], breg[8];
  #pragma unroll
  for (int q = 0; q < 8; ++q) {
    areg[q] = *(const float4*)(X  + aoff[q]);
    breg[q] = *(const float4*)(Wx + boff[q]);
  }

  for (int t = 0; t < NT; ++t) {
    __syncthreads();
    #pragma unroll
    for (int q = 0; q < 8; ++q) {
      *(uint2*)&A_lds[lrow[q] * LDK + kc4] = pk_bf16x4(areg[q]);
      *(uint2*)&B_lds[lrow[q] * LDK + kc4] = pk_bf16x4(breg[q]);
    }
    __syncthreads();
    if (t + 1 < NT) {
      const float* Ap = (t + 1 < 32) ? X  : Hx;
      const float* Wp = (t + 1 < 32) ? Wx : Wh;
      const int k0 = ((t + 1) & 31) * 64;
      #pragma unroll
      for (int q = 0; q < 8; ++q) {
        areg[q] = *(const float4*)(Ap + aoff[q] + k0);
        breg[q] = *(const float4*)(Wp + boff[q] + k0);
      }
    }
    #pragma unroll
    for (int ks = 0; ks < 2; ++ks) {
      short8 af[4], bfv[4];
      #pragma unroll
      for (int u = 0; u < 4; ++u)
        af[u] = *(const short8*)&A_lds[(wm * 64 + u * 16 + ln) * LDK + ks * 32 + quad * 8];
      #pragma unroll
      for (int u = 0; u < 4; ++u)
        bfv[u] = *(const short8*)&B_lds[(wn * 64 + u * 16 + ln) * LDK + ks * 32 + quad * 8];
      #pragma unroll
      for (int tm = 0; tm < 4; ++tm)
        #pragma unroll
        for (int tn = 0; tn < 4; ++tn)
          acc[tm][tn] = __builtin_amdgcn_mfma_f32_16x16x32_bf16(
              af[tm], bfv[tn], acc[tm][tn], 0, 0, 0);
    }
  }

  const int g = lane & 3;
  float biasv[4];
  int   hgs[4];
  #pragma unroll
  for (int tn = 0; tn < 4; ++tn) {
    int c  = wn * 64 + tn * 16 + ln;
    int hg = h0 + (c >> 2);
    hgs[tn] = hg;
    int j = g * HID + hg;
    biasv[tn] = bx[j] + bh[j];
  }
  #pragma unroll
  for (int tm = 0; tm < 4; ++tm) {
    #pragma unroll
    for (int r = 0; r < 4; ++r) {
      int mrow = m0 + wm * 64 + tm * 16 + quad * 4 + r;
      #pragma unroll
      for (int tn = 0; tn < 4; ++tn) {
        float v   = acc[tm][tn][r] + biasv[tn];
        float act = (g == 2) ? tanhx(v) : sigm(v);
        float y1 = __shfl_xor(act, 1);
        float y2 = __shfl_xor(act, 2);
        float y3 = __shfl_xor(act, 3);
        float ft = (g == 0) ? act : ((g == 1) ? y1 : ((g == 2) ? y2 : y3));
        float it = (g == 1) ? act : ((g == 0) ? y1 : ((g == 3) ? y2 : y3));
        float gt = (g == 2) ? act : ((g == 3) ? y1 : ((g == 0) ? y2 : y3));
        float ot = (g == 3) ? act : ((g == 2) ? y1 : ((g == 1) ? y2 : y3));
        if (g < 2) {
          size_t off = (size_t)mrow * HID + hgs[tn];
          float cxv = Cx[off];
          float cyv = ft * cxv + it * gt;
          if (g == 0) Hy[off] = ot * tanhx(cyv);
          else        Cy[off] = cyv;
        }
      }
    }
  }
}

extern "C" void kernel_launch(void* const* d_in, const int* in_sizes, int n_in,
                              void* d_out, int out_size, void* d_ws, size_t ws_size,
                              hipStream_t stream) {
  const float* X  = (const float*)d_in[0];
  const float* Hx = (const float*)d_in[1];
  const float* Cx = (const float*)d_in[2];
  const float* Wx = (const float*)d_in[3];
  const float* bx = (const float*)d_in[4];
  const float* Wh = (const float*)d_in[5];
  const float* bh = (const float*)d_in[6];
  float*       Hy = (float*)d_out;
  float*       Cy = Hy + (size_t)BATCH * HID;

  const size_t needA = (size_t)BATCH * K4 * sizeof(short);     // 32 MiB
  const size_t needB = (size_t)(4 * HID) * K4 * sizeof(short); // 64 MiB

  if (d_ws != nullptr && ws_size >= needA + needB) {
    short* Abf = (short*)d_ws;
    short* Bbf = (short*)((char*)d_ws + needA);
    conv_a<<<dim3((BATCH * (K4 / 8)) / 256), dim3(256), 0, stream>>>(X, Hx, Abf);
    conv_b<<<dim3((4 * HID * (K4 / 8)) / 256), dim3(256), 0, stream>>>(Wx, Wh, Bbf);
    dim3 grid(BATCH / 256, (4 * HID) / 256, 1);  // 16 x 32; x fastest
    lstm_mm8<<<grid, dim3(512, 1, 1), 0, stream>>>(Abf, Bbf, Cx, bx, bh, Hy, Cy);
  } else {
    dim3 grid(BATCH / 128, HID / 32, 1);
    lstm_cell_fallback<<<grid, dim3(256, 1, 1), 0, stream>>>(X, Hx, Cx, Wx, bx, Wh, bh, Hy, Cy);
  }
}

// Round 5
// 576.748 us; speedup vs baseline: 1.0314x; 1.0145x over previous
//
#include <hip/hip_runtime.h>
#include <hip/hip_bf16.h>

// LSTM cell, R8: 256^2 dbuf GEMM with RELAXED barriers (2 per half-tile).
// R5/R6/R7 post-mortem: per-phase asm("memory") barriers forced lockstep
// {all-waves-read | all-waves-MFMA} serialization -> LDS pipe and MFMA pipe
// never overlapped -> 14.4k cy/iter vs ~6k LDS-bound ideal. R8 removes all
// intra-tile barriers: per half-K-tile, issue all 24 ds_reads as plain loads
// and 4 MFMA quadrants in read order (compiler emits counted lgkmcnt and
// interleaves; waves free-run). Barriers only at buffer switch:
//   BAR (all waves' reads of d done) -> stage d<-T+2 (8 gload16)
//   -> VMC(8) (other dbuf landed, 1-half lead; tail: VMC(0)) -> BAR.
// Staging geometry, XOR slot swizzle (0 conflicts), conv passes, epilogue
// all unchanged from R5/R7.

#define BATCH 4096
#define HID   2048
#define KDIM  2048
#define K4    4096
#define LDK   72      // fallback kernel's padded LDS stride

typedef __attribute__((ext_vector_type(8))) short  short8;
typedef __attribute__((ext_vector_type(4))) float  f32x4;

__device__ __forceinline__ float sigm(float x)  { return 1.f / (1.f + __expf(-x)); }
__device__ __forceinline__ float tanhx(float x) { return 2.f / (1.f + __expf(-2.f * x)) - 1.f; }

__device__ __forceinline__ uint2 pk_bf16x4(float4 v) {
  __hip_bfloat162 lo = __float22bfloat162_rn(make_float2(v.x, v.y));
  __hip_bfloat162 hi = __float22bfloat162_rn(make_float2(v.z, v.w));
  uint2 r;
  r.x = *(unsigned*)&lo;
  r.y = *(unsigned*)&hi;
  return r;
}

__device__ __forceinline__ void gload16(const void* g, void* l) {
  __builtin_amdgcn_global_load_lds(
      (const __attribute__((address_space(1))) unsigned int*)g,
      (__attribute__((address_space(3))) unsigned int*)l, 16, 0, 0);
}

#define BAR()  asm volatile("s_barrier" ::: "memory")
#define VMC(n) asm volatile("s_waitcnt vmcnt(" #n ")" ::: "memory")

// ---------------- conversion pass 1: Acat = bf16([X | Hx]) ------------------
__global__ __launch_bounds__(256) void conv_a(const float* __restrict__ X,
                                              const float* __restrict__ Hx,
                                              short* __restrict__ A) {
  const int gid = blockIdx.x * 256 + threadIdx.x;
  const int m   = gid >> 9;
  const int pos = (gid & 511) << 3;
  const float* src = (pos < KDIM) ? X  + (size_t)m * KDIM + pos
                                  : Hx + (size_t)m * KDIM + (pos - KDIM);
  float4 v0 = *(const float4*)src;
  float4 v1 = *(const float4*)(src + 4);
  uint2 p0 = pk_bf16x4(v0), p1 = pk_bf16x4(v1);
  uint4 o; o.x = p0.x; o.y = p0.y; o.z = p1.x; o.w = p1.y;
  *(uint4*)(A + (size_t)gid * 8) = o;
}

// ------ conversion pass 2: Bcat[j'=4h+g][k] = bf16([Wx | Wh][g*2048+h]) -----
__global__ __launch_bounds__(256) void conv_b(const float* __restrict__ Wx,
                                              const float* __restrict__ Wh,
                                              short* __restrict__ Bm) {
  const int gid = blockIdx.x * 256 + threadIdx.x;
  const int jp  = gid >> 9;
  const int pos = (gid & 511) << 3;
  const int srow = (jp & 3) * HID + (jp >> 2);
  const float* src = (pos < KDIM) ? Wx + (size_t)srow * KDIM + pos
                                  : Wh + (size_t)srow * KDIM + (pos - KDIM);
  float4 v0 = *(const float4*)src;
  float4 v1 = *(const float4*)(src + 4);
  uint2 p0 = pk_bf16x4(v0), p1 = pk_bf16x4(v1);
  uint4 o; o.x = p0.x; o.y = p0.y; o.z = p1.x; o.w = p1.y;
  *(uint4*)(Bm + (size_t)gid * 8) = o;
}

// ---------------- helpers ----------------------------------------------------
__device__ __forceinline__ void lda4(short8 (&dst)[8], const short* base,
                                     int arow, int sx0, int sx1, int mfb) {
  #pragma unroll
  for (int u = 0; u < 4; ++u) {
    dst[u]     = *(const short8*)&base[arow + (mfb + u) * 1024 + sx0];
    dst[4 + u] = *(const short8*)&base[arow + (mfb + u) * 1024 + sx1];
  }
}
__device__ __forceinline__ void ldb2(short8 (&dst)[4], const short* base,
                                     int brow, int sx0, int sx1, int nfb) {
  #pragma unroll
  for (int v = 0; v < 2; ++v) {
    dst[v]     = *(const short8*)&base[brow + (nfb + v) * 1024 + sx0];
    dst[2 + v] = *(const short8*)&base[brow + (nfb + v) * 1024 + sx1];
  }
}
__device__ __forceinline__ void mmq(f32x4 (&acc)[8][4], const short8 (&A)[8],
                                    const short8 (&B)[4], int MB, int NB) {
  __builtin_amdgcn_s_setprio(1);
  #pragma unroll
  for (int ks = 0; ks < 2; ++ks)
    #pragma unroll
    for (int u = 0; u < 4; ++u)
      #pragma unroll
      for (int v = 0; v < 2; ++v)
        acc[MB + u][NB + v] = __builtin_amdgcn_mfma_f32_16x16x32_bf16(
            A[ks * 4 + u], B[ks * 2 + v], acc[MB + u][NB + v], 0, 0, 0);
  __builtin_amdgcn_s_setprio(0);
}

// ---------------- main GEMM + LSTM epilogue (256^2, relaxed dbuf) -----------
__global__ __launch_bounds__(512, 2) void lstm_mm8(
    const short* __restrict__ A, const short* __restrict__ Bm,
    const float* __restrict__ Cx,
    const float* __restrict__ bx, const float* __restrict__ bh,
    float* __restrict__ Hy, float* __restrict__ Cy)
{
  __shared__ __align__(16) short A_sh[2 * 16384];  // [d][256 rows][64], 64 KiB
  __shared__ __align__(16) short B_sh[2 * 16384];  // [d][256 rows][64], 64 KiB

  const int tid  = threadIdx.x;
  const int wv   = tid >> 6;         // 0..7
  const int lane = tid & 63;
  const int quad = lane >> 4;
  const int ln   = lane & 15;
  const int wm   = wv >> 2;          // 2 waves in M
  const int wn   = wv & 3;           // 4 waves in N
  const int m0   = blockIdx.x * 256;
  const int j0   = blockIdx.y * 256; // = 4 * h0
  const int h0   = blockIdx.y * 64;

  f32x4 acc[8][4];
  #pragma unroll
  for (int a = 0; a < 8; ++a)
    #pragma unroll
    for (int b = 0; b < 4; ++b)
      acc[a][b] = (f32x4){0.f, 0.f, 0.f, 0.f};

  // staging: per wave one half-slice per matrix; LDS dest linear, global
  // source pre-swizzled (slot ^ row&7). 8 gload16 per thread per tile.
  const int l8  = lane >> 3;
  const int swz = ((lane & 7) ^ (l8 & 7)) << 3;
  const short* aG = A  + (size_t)(m0 + l8) * K4 + swz;
  const short* bG = Bm + (size_t)(j0 + l8) * K4 + swz;

  #define STAGE_A(d, h, tau) do {                                             \
    gload16(aG + ((size_t)((h)*128 + wv*16    )) * K4 + (tau)*64,             \
            &A_sh[(d)*16384 + (h)*8192 + wv*1024]);                           \
    gload16(aG + ((size_t)((h)*128 + wv*16 + 8)) * K4 + (tau)*64,             \
            &A_sh[(d)*16384 + (h)*8192 + wv*1024 + 512]);                     \
  } while (0)
  #define STAGE_B(d, h, tau) do {                                             \
    gload16(bG + ((size_t)((h)*128 + wv*16    )) * K4 + (tau)*64,             \
            &B_sh[(d)*16384 + (h)*8192 + wv*1024]);                           \
    gload16(bG + ((size_t)((h)*128 + wv*16 + 8)) * K4 + (tau)*64,             \
            &B_sh[(d)*16384 + (h)*8192 + wv*1024 + 512]);                     \
  } while (0)
  #define STAGE_TILE(d, tau) do {                                             \
    STAGE_A(d, 0, tau); STAGE_A(d, 1, tau);                                   \
    STAGE_B(d, 0, tau); STAGE_B(d, 1, tau);                                   \
  } while (0)

  // ds_read geometry (XOR slot swizzle; measured 0 bank conflicts)
  const int arow = (wm * 128 + ln) * 64;   // shorts
  const int brow = (wn * 64  + ln) * 64;
  const int sx0  = ((0 + quad) ^ (ln & 7)) << 3;
  const int sx1  = ((4 + quad) ^ (ln & 7)) << 3;

  // prologue: tile0 -> dbuf0, tile1 -> dbuf1; vmcnt(8) => tile0 landed.
  STAGE_TILE(0, 0);
  STAGE_TILE(1, 1);
  VMC(8);
  BAR();

  short8 aQ0[8], aQ1[8], bLo[4], bHi[4];

  // Half-K-tile body: 24 plain ds_reads + 4 MFMA quadrants in read order
  // (compiler emits counted lgkmcnt; waves free-run). Then the only sync:
  // BAR -> stage this dbuf's next tile -> VMC -> BAR.
  #define HALF(D, stageIt, d, tauNext, gateN) do {                            \
    lda4(aQ0, &A_sh[D], arow, sx0, sx1, 0);                                   \
    ldb2(bLo, &B_sh[D], brow, sx0, sx1, 0);                                   \
    lda4(aQ1, &A_sh[D], arow, sx0, sx1, 4);                                   \
    ldb2(bHi, &B_sh[D], brow, sx0, sx1, 2);                                   \
    mmq(acc, aQ0, bLo, 0, 0);                                                 \
    mmq(acc, aQ1, bLo, 4, 0);                                                 \
    mmq(acc, aQ1, bHi, 4, 2);                                                 \
    mmq(acc, aQ0, bHi, 0, 2);                                                 \
    BAR();                                                                    \
    if (stageIt) { STAGE_TILE(d, tauNext); VMC(8); } else { VMC(gateN); }     \
    BAR();                                                                    \
  } while (0)

  #pragma unroll 1
  for (int i = 0; i < 32; ++i) {
    const bool nl = (i != 31);
    // half-A: compute dbuf0 (tile 2i); restage dbuf0 <- tile 2i+2
    HALF(0,     nl, 0, 2 * i + 2, 0);
    // half-B: compute dbuf1 (tile 2i+1); restage dbuf1 <- tile 2i+3
    HALF(16384, nl, 1, 2 * i + 3, 0);
  }
  #undef HALF
  #undef STAGE_TILE
  #undef STAGE_B
  #undef STAGE_A

  // ---- epilogue: C/D layout col = lane&15 (c), row = quad*4 + reg ----
  const int g = lane & 3;            // gate of this lane (c&3)
  float biasv[4];
  int   hgs[4];
  #pragma unroll
  for (int nf = 0; nf < 4; ++nf) {
    int c  = wn * 64 + nf * 16 + ln;
    int hg = h0 + (c >> 2);
    hgs[nf] = hg;
    int j = g * HID + hg;
    biasv[nf] = bx[j] + bh[j];
  }
  #pragma unroll
  for (int mf = 0; mf < 8; ++mf) {
    #pragma unroll
    for (int r = 0; r < 4; ++r) {
      int mrow = m0 + wm * 128 + mf * 16 + quad * 4 + r;
      #pragma unroll
      for (int nf = 0; nf < 4; ++nf) {
        float v   = acc[mf][nf][r] + biasv[nf];
        float act = (g == 2) ? tanhx(v) : sigm(v);
        float y1 = __shfl_xor(act, 1);
        float y2 = __shfl_xor(act, 2);
        float y3 = __shfl_xor(act, 3);
        float ft = (g == 0) ? act : ((g == 1) ? y1 : ((g == 2) ? y2 : y3));
        float it = (g == 1) ? act : ((g == 0) ? y1 : ((g == 3) ? y2 : y3));
        float gt = (g == 2) ? act : ((g == 3) ? y1 : ((g == 0) ? y2 : y3));
        float ot = (g == 3) ? act : ((g == 2) ? y1 : ((g == 1) ? y2 : y3));
        if (g < 2) {
          size_t off = (size_t)mrow * HID + hgs[nf];
          float cxv = Cx[off];
          float cyv = ft * cxv + it * gt;
          if (g == 0) Hy[off] = ot * tanhx(cyv);
          else        Cy[off] = cyv;
        }
      }
    }
  }
}

// ---------------- fallback: R3 kernel (register staging, fp32 in) ----------
__global__ __launch_bounds__(256) void lstm_cell_fallback(
    const float* __restrict__ X, const float* __restrict__ Hx,
    const float* __restrict__ Cx,
    const float* __restrict__ Wx, const float* __restrict__ bx,
    const float* __restrict__ Wh, const float* __restrict__ bh,
    float* __restrict__ Hy, float* __restrict__ Cy)
{
  __shared__ __align__(16) short A_lds[128 * LDK];
  __shared__ __align__(16) short B_lds[128 * LDK];

  const int tid  = threadIdx.x;
  const int wv   = tid >> 6;
  const int lane = tid & 63;
  const int quad = lane >> 4;
  const int ln   = lane & 15;
  const int wm   = wv >> 1;
  const int wn   = wv & 1;
  const int m0   = blockIdx.x * 128;
  const int h0   = blockIdx.y * 32;

  f32x4 acc[4][4];
  #pragma unroll
  for (int a = 0; a < 4; ++a)
    #pragma unroll
    for (int b = 0; b < 4; ++b)
      acc[a][b] = (f32x4){0.f, 0.f, 0.f, 0.f};

  const int rA  = tid >> 4;
  const int kc4 = (tid & 15) * 4;
  size_t aoff[8], boff[8];
  int    lrow[8];
  #pragma unroll
  for (int q = 0; q < 8; ++q) {
    int row  = q * 16 + rA;
    lrow[q]  = row;
    aoff[q]  = (size_t)(m0 + row) * KDIM + kc4;
    int wrow = (row & 3) * HID + h0 + (row >> 2);
    boff[q]  = (size_t)wrow * KDIM + kc4;
  }

  const int NT = 2 * (KDIM / 64);
  float4 areg[8], breg[8];
  #pragma unroll
  for (int q = 0; q < 8; ++q) {
    areg[q] = *(const float4*)(X  + aoff[q]);
    breg[q] = *(const float4*)(Wx + boff[q]);
  }

  for (int t = 0; t < NT; ++t) {
    __syncthreads();
    #pragma unroll
    for (int q = 0; q < 8; ++q) {
      *(uint2*)&A_lds[lrow[q] * LDK + kc4] = pk_bf16x4(areg[q]);
      *(uint2*)&B_lds[lrow[q] * LDK + kc4] = pk_bf16x4(breg[q]);
    }
    __syncthreads();
    if (t + 1 < NT) {
      const float* Ap = (t + 1 < 32) ? X  : Hx;
      const float* Wp = (t + 1 < 32) ? Wx : Wh;
      const int k0 = ((t + 1) & 31) * 64;
      #pragma unroll
      for (int q = 0; q < 8; ++q) {
        areg[q] = *(const float4*)(Ap + aoff[q] + k0);
        breg[q] = *(const float4*)(Wp + boff[q] + k0);
      }
    }
    #pragma unroll
    for (int ks = 0; ks < 2; ++ks) {
      short8 af[4], bfv[4];
      #pragma unroll
      for (int u = 0; u < 4; ++u)
        af[u] = *(const short8*)&A_lds[(wm * 64 + u * 16 + ln) * LDK + ks * 32 + quad * 8];
      #pragma unroll
      for (int u = 0; u < 4; ++u)
        bfv[u] = *(const short8*)&B_lds[(wn * 64 + u * 16 + ln) * LDK + ks * 32 + quad * 8];
      #pragma unroll
      for (int tm = 0; tm < 4; ++tm)
        #pragma unroll
        for (int tn = 0; tn < 4; ++tn)
          acc[tm][tn] = __builtin_amdgcn_mfma_f32_16x16x32_bf16(
              af[tm], bfv[tn], acc[tm][tn], 0, 0, 0);
    }
  }

  const int g = lane & 3;
  float biasv[4];
  int   hgs[4];
  #pragma unroll
  for (int tn = 0; tn < 4; ++tn) {
    int c  = wn * 64 + tn * 16 + ln;
    int hg = h0 + (c >> 2);
    hgs[tn] = hg;
    int j = g * HID + hg;
    biasv[tn] = bx[j] + bh[j];
  }
  #pragma unroll
  for (int tm = 0; tm < 4; ++tm) {
    #pragma unroll
    for (int r = 0; r < 4; ++r) {
      int mrow = m0 + wm * 64 + tm * 16 + quad * 4 + r;
      #pragma unroll
      for (int tn = 0; tn < 4; ++tn) {
        float v   = acc[tm][tn][r] + biasv[tn];
        float act = (g == 2) ? tanhx(v) : sigm(v);
        float y1 = __shfl_xor(act, 1);
        float y2 = __shfl_xor(act, 2);
        float y3 = __shfl_xor(act, 3);
        float ft = (g == 0) ? act : ((g == 1) ? y1 : ((g == 2) ? y2 : y3));
        float it = (g == 1) ? act : ((g == 0) ? y1 : ((g == 3) ? y2 : y3));
        float gt = (g == 2) ? act : ((g == 3) ? y1 : ((g == 0) ? y2 : y3));
        float ot = (g == 3) ? act : ((g == 2) ? y1 : ((g == 1) ? y2 : y3));
        if (g < 2) {
          size_t off = (size_t)mrow * HID + hgs[tn];
          float cxv = Cx[off];
          float cyv = ft * cxv + it * gt;
          if (g == 0) Hy[off] = ot * tanhx(cyv);
          else        Cy[off] = cyv;
        }
      }
    }
  }
}

extern "C" void kernel_launch(void* const* d_in, const int* in_sizes, int n_in,
                              void* d_out, int out_size, void* d_ws, size_t ws_size,
                              hipStream_t stream) {
  const float* X  = (const float*)d_in[0];
  const float* Hx = (const float*)d_in[1];
  const float* Cx = (const float*)d_in[2];
  const float* Wx = (const float*)d_in[3];
  const float* bx = (const float*)d_in[4];
  const float* Wh = (const float*)d_in[5];
  const float* bh = (const float*)d_in[6];
  float*       Hy = (float*)d_out;
  float*       Cy = Hy + (size_t)BATCH * HID;

  const size_t needA = (size_t)BATCH * K4 * sizeof(short);     // 32 MiB
  const size_t needB = (size_t)(4 * HID) * K4 * sizeof(short); // 64 MiB

  if (d_ws != nullptr && ws_size >= needA + needB) {
    short* Abf = (short*)d_ws;
    short* Bbf = (short*)((char*)d_ws + needA);
    conv_a<<<dim3((BATCH * (K4 / 8)) / 256), dim3(256), 0, stream>>>(X, Hx, Abf);
    conv_b<<<dim3((4 * HID * (K4 / 8)) / 256), dim3(256), 0, stream>>>(Wx, Wh, Bbf);
    dim3 grid(BATCH / 256, (4 * HID) / 256, 1);  // 16 x 32; x fastest
    lstm_mm8<<<grid, dim3(512, 1, 1), 0, stream>>>(Abf, Bbf, Cx, bx, bh, Hy, Cy);
  } else {
    dim3 grid(BATCH / 128, HID / 32, 1);
    lstm_cell_fallback<<<grid, dim3(256, 1, 1), 0, stream>>>(X, Hx, Cx, Wx, bx, Wh, bh, Hy, Cy);
  }
}

// Round 6
// 576.227 us; speedup vs baseline: 1.0323x; 1.0009x over previous
//
#include <hip/hip_runtime.h>
#include <hip/hip_bf16.h>

// LSTM cell, R9 = R8 GEMM + TILE-CONTIGUOUS workspace layout.
// R5-R8 post-mortem: four schedule variants (lockstep / XCD-swizzle /
// uniform-lead / relaxed) all pin at 375-385us, MfmaUtil ~31% -> limiter is
// below the schedule. Common factor: staging reads stride 8 KiB per row
// (row*K4*2B) -> one gload_lds touches 8 scattered 128B chunks; 8KiB pow-2
// stride = worst case for L2 channel interleave -> staging arrival-rate-bound.
// R9: workspace re-laid as 32KiB slabs [tile(mt,kt)][h][wv][q][l8][slot] =
// the exact linear LDS image (XOR slot swizzle pre-applied at conv time).
// Each gload16 reads 1KiB contiguous; blocks stream consecutive slabs.
// LDS image verified bit-identical to R8 (slot p of row r holds chunk
// p^(r&7)); ds_read geometry + epilogue untouched. conv_a+conv_b fused.

#define BATCH 4096
#define HID   2048
#define KDIM  2048
#define K4    4096
#define LDK   72      // fallback kernel's padded LDS stride

typedef __attribute__((ext_vector_type(8))) short  short8;
typedef __attribute__((ext_vector_type(4))) float  f32x4;

__device__ __forceinline__ float sigm(float x)  { return 1.f / (1.f + __expf(-x)); }
__device__ __forceinline__ float tanhx(float x) { return 2.f / (1.f + __expf(-2.f * x)) - 1.f; }

__device__ __forceinline__ uint2 pk_bf16x4(float4 v) {
  __hip_bfloat162 lo = __float22bfloat162_rn(make_float2(v.x, v.y));
  __hip_bfloat162 hi = __float22bfloat162_rn(make_float2(v.z, v.w));
  uint2 r;
  r.x = *(unsigned*)&lo;
  r.y = *(unsigned*)&hi;
  return r;
}

__device__ __forceinline__ void gload16(const void* g, void* l) {
  __builtin_amdgcn_global_load_lds(
      (const __attribute__((address_space(1))) unsigned int*)g,
      (__attribute__((address_space(3))) unsigned int*)l, 16, 0, 0);
}

#define BAR()  asm volatile("s_barrier" ::: "memory")
#define VMC(n) asm volatile("s_waitcnt vmcnt(" #n ")" ::: "memory")

// ---- fused conversion: fp32 inputs -> bf16 tile-contiguous slabs -----------
// Slab layout (shorts): ws[(tile)*16384 + h*8192 + wv*1024 + q*512 + l8*64 + p*8]
//   tile = bt*64 + kt; row = bt*256 + h*128 + wv*16 + q*8 + l8;
//   k = kt*64 + (p ^ l8)*8   (XOR slot swizzle pre-applied).
// A chunks: 16 m-tiles * 64 kt * 2048 = 2,097,152; B: 32 n-tiles -> 4,194,304.
#define ACHUNKS (16 * 64 * 2048)
#define BCHUNKS (32 * 64 * 2048)

__global__ __launch_bounds__(256) void conv_pack(
    const float* __restrict__ X,  const float* __restrict__ Hx,
    const float* __restrict__ Wx, const float* __restrict__ Wh,
    short* __restrict__ At, short* __restrict__ Bt) {
  const int gid = blockIdx.x * 256 + threadIdx.x;
  const bool isA = gid < ACHUNKS;
  const int c  = isA ? gid : gid - ACHUNKS;
  const int t  = c >> 11;          // tile index bt*64+kt
  const int w  = c & 2047;         // chunk within tile
  const int bt = t >> 6;
  const int kt = t & 63;
  const int h  = w >> 10;
  const int wvv= (w >> 7) & 7;
  const int q  = (w >> 6) & 1;
  const int l8 = (w >> 3) & 7;
  const int p  = w & 7;
  const int row = bt * 256 + h * 128 + wvv * 16 + q * 8 + l8;
  const int k   = kt * 64 + ((p ^ l8) << 3);
  const float* src;
  if (isA) {
    src = (k < KDIM) ? X + (size_t)row * KDIM + k
                     : Hx + (size_t)row * KDIM + (k - KDIM);
  } else {
    const int srow = (row & 3) * HID + (row >> 2);   // gate*2048 + h
    src = (k < KDIM) ? Wx + (size_t)srow * KDIM + k
                     : Wh + (size_t)srow * KDIM + (k - KDIM);
  }
  float4 v0 = *(const float4*)src;
  float4 v1 = *(const float4*)(src + 4);
  uint2 p0 = pk_bf16x4(v0), p1 = pk_bf16x4(v1);
  uint4 o; o.x = p0.x; o.y = p0.y; o.z = p1.x; o.w = p1.y;
  short* dst = isA ? At : Bt;
  *(uint4*)(dst + (size_t)c * 8) = o;
}

// ---------------- helpers ----------------------------------------------------
__device__ __forceinline__ void lda4(short8 (&dst)[8], const short* base,
                                     int arow, int sx0, int sx1, int mfb) {
  #pragma unroll
  for (int u = 0; u < 4; ++u) {
    dst[u]     = *(const short8*)&base[arow + (mfb + u) * 1024 + sx0];
    dst[4 + u] = *(const short8*)&base[arow + (mfb + u) * 1024 + sx1];
  }
}
__device__ __forceinline__ void ldb2(short8 (&dst)[4], const short* base,
                                     int brow, int sx0, int sx1, int nfb) {
  #pragma unroll
  for (int v = 0; v < 2; ++v) {
    dst[v]     = *(const short8*)&base[brow + (nfb + v) * 1024 + sx0];
    dst[2 + v] = *(const short8*)&base[brow + (nfb + v) * 1024 + sx1];
  }
}
__device__ __forceinline__ void mmq(f32x4 (&acc)[8][4], const short8 (&A)[8],
                                    const short8 (&B)[4], int MB, int NB) {
  __builtin_amdgcn_s_setprio(1);
  #pragma unroll
  for (int ks = 0; ks < 2; ++ks)
    #pragma unroll
    for (int u = 0; u < 4; ++u)
      #pragma unroll
      for (int v = 0; v < 2; ++v)
        acc[MB + u][NB + v] = __builtin_amdgcn_mfma_f32_16x16x32_bf16(
            A[ks * 4 + u], B[ks * 2 + v], acc[MB + u][NB + v], 0, 0, 0);
  __builtin_amdgcn_s_setprio(0);
}

// ---------------- main GEMM + LSTM epilogue (256^2, relaxed dbuf) -----------
__global__ __launch_bounds__(512, 2) void lstm_mm8(
    const short* __restrict__ At, const short* __restrict__ Bt,
    const float* __restrict__ Cx,
    const float* __restrict__ bx, const float* __restrict__ bh,
    float* __restrict__ Hy, float* __restrict__ Cy)
{
  __shared__ __align__(16) short A_sh[2 * 16384];  // [d][256 rows][64], 64 KiB
  __shared__ __align__(16) short B_sh[2 * 16384];  // [d][256 rows][64], 64 KiB

  const int tid  = threadIdx.x;
  const int wv   = tid >> 6;         // 0..7
  const int lane = tid & 63;
  const int quad = lane >> 4;
  const int ln   = lane & 15;
  const int wm   = wv >> 2;          // 2 waves in M
  const int wn   = wv & 3;           // 4 waves in N
  const int m0   = blockIdx.x * 256;
  const int h0   = blockIdx.y * 64;

  f32x4 acc[8][4];
  #pragma unroll
  for (int a = 0; a < 8; ++a)
    #pragma unroll
    for (int b = 0; b < 4; ++b)
      acc[a][b] = (f32x4){0.f, 0.f, 0.f, 0.f};

  // tile-contiguous staging: slab (bt*64+kt) is 32 KiB contiguous; each
  // gload16 copies 1 KiB contiguous (lane*16B) into the linear LDS dest.
  const short* aT = At + ((size_t)blockIdx.x * 64) * 16384 + lane * 8;
  const short* bT = Bt + ((size_t)blockIdx.y * 64) * 16384 + lane * 8;

  #define STAGE_A(d, h, tau) do {                                             \
    gload16(aT + (size_t)(tau) * 16384 + (h) * 8192 + wv * 1024,              \
            &A_sh[(d)*16384 + (h)*8192 + wv*1024]);                           \
    gload16(aT + (size_t)(tau) * 16384 + (h) * 8192 + wv * 1024 + 512,        \
            &A_sh[(d)*16384 + (h)*8192 + wv*1024 + 512]);                     \
  } while (0)
  #define STAGE_B(d, h, tau) do {                                             \
    gload16(bT + (size_t)(tau) * 16384 + (h) * 8192 + wv * 1024,              \
            &B_sh[(d)*16384 + (h)*8192 + wv*1024]);                           \
    gload16(bT + (size_t)(tau) * 16384 + (h) * 8192 + wv * 1024 + 512,        \
            &B_sh[(d)*16384 + (h)*8192 + wv*1024 + 512]);                     \
  } while (0)
  #define STAGE_TILE(d, tau) do {                                             \
    STAGE_A(d, 0, tau); STAGE_A(d, 1, tau);                                   \
    STAGE_B(d, 0, tau); STAGE_B(d, 1, tau);                                   \
  } while (0)

  // ds_read geometry (XOR slot swizzle; measured 0 bank conflicts)
  const int arow = (wm * 128 + ln) * 64;   // shorts
  const int brow = (wn * 64  + ln) * 64;
  const int sx0  = ((0 + quad) ^ (ln & 7)) << 3;
  const int sx1  = ((4 + quad) ^ (ln & 7)) << 3;

  // prologue: tile0 -> dbuf0, tile1 -> dbuf1; vmcnt(8) => tile0 landed.
  STAGE_TILE(0, 0);
  STAGE_TILE(1, 1);
  VMC(8);
  BAR();

  short8 aQ0[8], aQ1[8], bLo[4], bHi[4];

  // Half-K-tile body: 24 plain ds_reads + 4 MFMA quadrants (compiler emits
  // counted lgkmcnt; waves free-run). Sync only at buffer switch:
  // BAR -> stage this dbuf's next tile -> VMC -> BAR.
  #define HALF(D, stageIt, d, tauNext, gateN) do {                            \
    lda4(aQ0, &A_sh[D], arow, sx0, sx1, 0);                                   \
    ldb2(bLo, &B_sh[D], brow, sx0, sx1, 0);                                   \
    lda4(aQ1, &A_sh[D], arow, sx0, sx1, 4);                                   \
    ldb2(bHi, &B_sh[D], brow, sx0, sx1, 2);                                   \
    mmq(acc, aQ0, bLo, 0, 0);                                                 \
    mmq(acc, aQ1, bLo, 4, 0);                                                 \
    mmq(acc, aQ1, bHi, 4, 2);                                                 \
    mmq(acc, aQ0, bHi, 0, 2);                                                 \
    BAR();                                                                    \
    if (stageIt) { STAGE_TILE(d, tauNext); VMC(8); } else { VMC(gateN); }     \
    BAR();                                                                    \
  } while (0)

  #pragma unroll 1
  for (int i = 0; i < 32; ++i) {
    const bool nl = (i != 31);
    HALF(0,     nl, 0, 2 * i + 2, 0);   // compute dbuf0 (tile 2i)
    HALF(16384, nl, 1, 2 * i + 3, 0);   // compute dbuf1 (tile 2i+1)
  }
  #undef HALF
  #undef STAGE_TILE
  #undef STAGE_B
  #undef STAGE_A

  // ---- epilogue: C/D layout col = lane&15 (c), row = quad*4 + reg ----
  const int g = lane & 3;            // gate of this lane (c&3)
  float biasv[4];
  int   hgs[4];
  #pragma unroll
  for (int nf = 0; nf < 4; ++nf) {
    int c  = wn * 64 + nf * 16 + ln;
    int hg = h0 + (c >> 2);
    hgs[nf] = hg;
    int j = g * HID + hg;
    biasv[nf] = bx[j] + bh[j];
  }
  #pragma unroll
  for (int mf = 0; mf < 8; ++mf) {
    #pragma unroll
    for (int r = 0; r < 4; ++r) {
      int mrow = m0 + wm * 128 + mf * 16 + quad * 4 + r;
      #pragma unroll
      for (int nf = 0; nf < 4; ++nf) {
        float v   = acc[mf][nf][r] + biasv[nf];
        float act = (g == 2) ? tanhx(v) : sigm(v);
        float y1 = __shfl_xor(act, 1);
        float y2 = __shfl_xor(act, 2);
        float y3 = __shfl_xor(act, 3);
        float ft = (g == 0) ? act : ((g == 1) ? y1 : ((g == 2) ? y2 : y3));
        float it = (g == 1) ? act : ((g == 0) ? y1 : ((g == 3) ? y2 : y3));
        float gt = (g == 2) ? act : ((g == 3) ? y1 : ((g == 0) ? y2 : y3));
        float ot = (g == 3) ? act : ((g == 2) ? y1 : ((g == 1) ? y2 : y3));
        if (g < 2) {
          size_t off = (size_t)mrow * HID + hgs[nf];
          float cxv = Cx[off];
          float cyv = ft * cxv + it * gt;
          if (g == 0) Hy[off] = ot * tanhx(cyv);
          else        Cy[off] = cyv;
        }
      }
    }
  }
}

// ---------------- fallback: R3 kernel (register staging, fp32 in) ----------
__global__ __launch_bounds__(256) void lstm_cell_fallback(
    const float* __restrict__ X, const float* __restrict__ Hx,
    const float* __restrict__ Cx,
    const float* __restrict__ Wx, const float* __restrict__ bx,
    const float* __restrict__ Wh, const float* __restrict__ bh,
    float* __restrict__ Hy, float* __restrict__ Cy)
{
  __shared__ __align__(16) short A_lds[128 * LDK];
  __shared__ __align__(16) short B_lds[128 * LDK];

  const int tid  = threadIdx.x;
  const int wv   = tid >> 6;
  const int lane = tid & 63;
  const int quad = lane >> 4;
  const int ln   = lane & 15;
  const int wm   = wv >> 1;
  const int wn   = wv & 1;
  const int m0   = blockIdx.x * 128;
  const int h0   = blockIdx.y * 32;

  f32x4 acc[4][4];
  #pragma unroll
  for (int a = 0; a < 4; ++a)
    #pragma unroll
    for (int b = 0; b < 4; ++b)
      acc[a][b] = (f32x4){0.f, 0.f, 0.f, 0.f};

  const int rA  = tid >> 4;
  const int kc4 = (tid & 15) * 4;
  size_t aoff[8], boff[8];
  int    lrow[8];
  #pragma unroll
  for (int q = 0; q < 8; ++q) {
    int row  = q * 16 + rA;
    lrow[q]  = row;
    aoff[q]  = (size_t)(m0 + row) * KDIM + kc4;
    int wrow = (row & 3) * HID + h0 + (row >> 2);
    boff[q]  = (size_t)wrow * KDIM + kc4;
  }

  const int NT = 2 * (KDIM / 64);
  float4 areg[8], breg[8];
  #pragma unroll
  for (int q = 0; q < 8; ++q) {
    areg[q] = *(const float4*)(X  + aoff[q]);
    breg[q] = *(const float4*)(Wx + boff[q]);
  }

  for (int t = 0; t < NT; ++t) {
    __syncthreads();
    #pragma unroll
    for (int q = 0; q < 8; ++q) {
      *(uint2*)&A_lds[lrow[q] * LDK + kc4] = pk_bf16x4(areg[q]);
      *(uint2*)&B_lds[lrow[q] * LDK + kc4] = pk_bf16x4(breg[q]);
    }
    __syncthreads();
    if (t + 1 < NT) {
      const float* Ap = (t + 1 < 32) ? X  : Hx;
      const float* Wp = (t + 1 < 32) ? Wx : Wh;
      const int k0 = ((t + 1) & 31) * 64;
      #pragma unroll
      for (int q = 0; q < 8; ++q) {
        areg[q] = *(const float4*)(Ap + aoff[q] + k0);
        breg[q] = *(const float4*)(Wp + boff[q] + k0);
      }
    }
    #pragma unroll
    for (int ks = 0; ks < 2; ++ks) {
      short8 af[4], bfv[4];
      #pragma unroll
      for (int u = 0; u < 4; ++u)
        af[u] = *(const short8*)&A_lds[(wm * 64 + u * 16 + ln) * LDK + ks * 32 + quad * 8];
      #pragma unroll
      for (int u = 0; u < 4; ++u)
        bfv[u] = *(const short8*)&B_lds[(wn * 64 + u * 16 + ln) * LDK + ks * 32 + quad * 8];
      #pragma unroll
      for (int tm = 0; tm < 4; ++tm)
        #pragma unroll
        for (int tn = 0; tn < 4; ++tn)
          acc[tm][tn] = __builtin_amdgcn_mfma_f32_16x16x32_bf16(
              af[tm], bfv[tn], acc[tm][tn], 0, 0, 0);
    }
  }

  const int g = lane & 3;
  float biasv[4];
  int   hgs[4];
  #pragma unroll
  for (int tn = 0; tn < 4; ++tn) {
    int c  = wn * 64 + tn * 16 + ln;
    int hg = h0 + (c >> 2);
    hgs[tn] = hg;
    int j = g * HID + hg;
    biasv[tn] = bx[j] + bh[j];
  }
  #pragma unroll
  for (int tm = 0; tm < 4; ++tm) {
    #pragma unroll
    for (int r = 0; r < 4; ++r) {
      int mrow = m0 + wm * 64 + tm * 16 + quad * 4 + r;
      #pragma unroll
      for (int tn = 0; tn < 4; ++tn) {
        float v   = acc[tm][tn][r] + biasv[tn];
        float act = (g == 2) ? tanhx(v) : sigm(v);
        float y1 = __shfl_xor(act, 1);
        float y2 = __shfl_xor(act, 2);
        float y3 = __shfl_xor(act, 3);
        float ft = (g == 0) ? act : ((g == 1) ? y1 : ((g == 2) ? y2 : y3));
        float it = (g == 1) ? act : ((g == 0) ? y1 : ((g == 3) ? y2 : y3));
        float gt = (g == 2) ? act : ((g == 3) ? y1 : ((g == 0) ? y2 : y3));
        float ot = (g == 3) ? act : ((g == 2) ? y1 : ((g == 1) ? y2 : y3));
        if (g < 2) {
          size_t off = (size_t)mrow * HID + hgs[tn];
          float cxv = Cx[off];
          float cyv = ft * cxv + it * gt;
          if (g == 0) Hy[off] = ot * tanhx(cyv);
          else        Cy[off] = cyv;
        }
      }
    }
  }
}

extern "C" void kernel_launch(void* const* d_in, const int* in_sizes, int n_in,
                              void* d_out, int out_size, void* d_ws, size_t ws_size,
                              hipStream_t stream) {
  const float* X  = (const float*)d_in[0];
  const float* Hx = (const float*)d_in[1];
  const float* Cx = (const float*)d_in[2];
  const float* Wx = (const float*)d_in[3];
  const float* bx = (const float*)d_in[4];
  const float* Wh = (const float*)d_in[5];
  const float* bh = (const float*)d_in[6];
  float*       Hy = (float*)d_out;
  float*       Cy = Hy + (size_t)BATCH * HID;

  const size_t needA = (size_t)ACHUNKS * 8 * sizeof(short);    // 32 MiB
  const size_t needB = (size_t)BCHUNKS * 8 * sizeof(short);    // 64 MiB

  if (d_ws != nullptr && ws_size >= needA + needB) {
    short* Abf = (short*)d_ws;
    short* Bbf = (short*)((char*)d_ws + needA);
    conv_pack<<<dim3((ACHUNKS + BCHUNKS) / 256), dim3(256), 0, stream>>>(
        X, Hx, Wx, Wh, Abf, Bbf);
    dim3 grid(BATCH / 256, (4 * HID) / 256, 1);  // 16 x 32; x fastest
    lstm_mm8<<<grid, dim3(512, 1, 1), 0, stream>>>(Abf, Bbf, Cx, bx, bh, Hy, Cy);
  } else {
    dim3 grid(BATCH / 128, HID / 32, 1);
    lstm_cell_fallback<<<grid, dim3(256, 1, 1), 0, stream>>>(X, Hx, Cx, Wx, bx, Wh, bh, Hy, Cy);
  }
}